// Round 1
// baseline (4580.802 us; speedup 1.0000x reference)
//
#include <hip/hip_runtime.h>
#include <math.h>

#define H 128

static const int SRC_T_[7] = {0, 0, 1, 1, 1, 2, 2};
static const int DST_T_[7] = {0, 1, 0, 1, 2, 1, 2};

__device__ __forceinline__ float eluf(float x) {
    return x > 0.f ? x : (__expf(x) - 1.f);
}

// ---------------------------------------------------------------------------
// h[t] = elu(x @ W + b); x:[n,64], W:[64,128], h:[n,128]
// block = 128 threads (thread j = output column), 16 rows per iteration.
__global__ __launch_bounds__(128) void k_input_linear(
    const float* __restrict__ x, const float* __restrict__ W,
    const float* __restrict__ b, float* __restrict__ h, int n)
{
    __shared__ float Ws[64 * H];   // 32 KB
    __shared__ float xs[16 * 64];  // 4 KB
    const int j = threadIdx.x;
    for (int i = j; i < 64 * H; i += 128) Ws[i] = W[i];
    const float bj = b[j];

    for (int r0 = blockIdx.x * 16; r0 < n; r0 += gridDim.x * 16) {
        const int nrows = min(16, n - r0);
        __syncthreads();
        for (int i = j; i < nrows * 64; i += 128) xs[i] = x[(size_t)r0 * 64 + i];
        __syncthreads();
        for (int i = 0; i < nrows; ++i) {
            float acc = bj;
#pragma unroll
            for (int k = 0; k < 64; k += 4) {
                float4 xv = *(const float4*)&xs[i * 64 + k];
                acc += xv.x * Ws[(k + 0) * H + j] + xv.y * Ws[(k + 1) * H + j]
                     + xv.z * Ws[(k + 2) * H + j] + xv.w * Ws[(k + 3) * H + j];
            }
            h[(size_t)(r0 + i) * H + j] = eluf(acc);
        }
    }
}

// ---------------------------------------------------------------------------
// msg = relu(h_src[src[e]] + ea[e] @ eW + eb); atomicAdd into agg[dst[e]].
// block = 256 threads = 2 edges per iteration (thread j = column).
__global__ __launch_bounds__(256) void k_edge(
    const int* __restrict__ src, const int* __restrict__ dst,
    const float* __restrict__ ea, const float* __restrict__ eW,
    const float* __restrict__ eb, const float* __restrict__ hsrc,
    float* __restrict__ agg, int E)
{
    const int j = threadIdx.x & 127;
    const int half = threadIdx.x >> 7;
    const float w0 = eW[j], w1 = eW[H + j], w2 = eW[2 * H + j], bj = eb[j];
    for (int e = blockIdx.x * 2 + half; e < E; e += gridDim.x * 2) {
        const int s = src[e], d = dst[e];
        const float a0 = ea[(size_t)e * 3 + 0];
        const float a1 = ea[(size_t)e * 3 + 1];
        const float a2 = ea[(size_t)e * 3 + 2];
        float m = hsrc[(size_t)s * H + j] + a0 * w0 + a1 * w1 + a2 * w2 + bj;
        m = fmaxf(m, 0.f);
        atomicAdd(&agg[(size_t)d * H + j], m);
    }
}

// ---------------------------------------------------------------------------
// z = h + agg; a1 = relu((z@W1 + b1)*bn_inv*g1 + be1); out (+)= a1@W2 + b2
// Dynamic LDS: W1s[16384] | W2s[16384] | zt[2048] | a1t[2048]  = 147456 B
// block = 512: j = tid&127 (column), q = tid>>7 (row-quarter, 4 rows each),
// 16 rows per iteration, grid-stride. 1 block/CU (LDS-bound).
#define MLP_SMEM 147456
__global__ __launch_bounds__(512, 1) void k_mlp(
    const float* __restrict__ hdst, const float* __restrict__ agg,
    const float* __restrict__ W1, const float* __restrict__ b1,
    const float* __restrict__ g1, const float* __restrict__ be1,
    const float* __restrict__ W2, const float* __restrict__ b2,
    float* __restrict__ out, int n, int init)
{
    extern __shared__ float smem[];
    float* W1s = smem;                  // 16384
    float* W2s = smem + 16384;          // 16384
    float* zt  = smem + 32768;          // 16*128
    float* a1t = smem + 32768 + 2048;   // 16*128

    const int tid = threadIdx.x;
    const int j = tid & 127;
    const int q = tid >> 7;            // 0..3
    const int rbase = q * 4;

    for (int i = tid; i < 16384; i += 512) { W1s[i] = W1[i]; W2s[i] = W2[i]; }
    const float bn_inv = 0.99999500003749977f;  // 1/sqrt(1 + 1e-5)
    const float b1j = b1[j], sj = g1[j] * bn_inv, bej = be1[j], b2j = b2[j];
    __syncthreads();

    for (int r0 = blockIdx.x * 16; r0 < n; r0 += gridDim.x * 16) {
        const int nrows = min(16, n - r0);
        // load z tile = h + agg (coalesced)
        for (int i = tid; i < nrows * H; i += 512)
            zt[i] = hdst[(size_t)r0 * H + i] + agg[(size_t)r0 * H + i];
        __syncthreads();  // A: zt ready (also fences prev iter's a1t reads)

        float acc0 = 0.f, acc1 = 0.f, acc2 = 0.f, acc3 = 0.f;
#pragma unroll 8
        for (int k = 0; k < H; k += 4) {
            float4 z0 = *(const float4*)&zt[(rbase + 0) * H + k];
            float4 z1 = *(const float4*)&zt[(rbase + 1) * H + k];
            float4 z2 = *(const float4*)&zt[(rbase + 2) * H + k];
            float4 z3 = *(const float4*)&zt[(rbase + 3) * H + k];
            const float w0 = W1s[(k + 0) * H + j], w1 = W1s[(k + 1) * H + j];
            const float w2 = W1s[(k + 2) * H + j], w3 = W1s[(k + 3) * H + j];
            acc0 += z0.x * w0 + z0.y * w1 + z0.z * w2 + z0.w * w3;
            acc1 += z1.x * w0 + z1.y * w1 + z1.z * w2 + z1.w * w3;
            acc2 += z2.x * w0 + z2.y * w1 + z2.z * w2 + z2.w * w3;
            acc3 += z3.x * w0 + z3.y * w1 + z3.z * w2 + z3.w * w3;
        }
        a1t[(rbase + 0) * H + j] = fmaxf((acc0 + b1j) * sj + bej, 0.f);
        a1t[(rbase + 1) * H + j] = fmaxf((acc1 + b1j) * sj + bej, 0.f);
        a1t[(rbase + 2) * H + j] = fmaxf((acc2 + b1j) * sj + bej, 0.f);
        a1t[(rbase + 3) * H + j] = fmaxf((acc3 + b1j) * sj + bej, 0.f);
        __syncthreads();  // B: a1t ready

        acc0 = acc1 = acc2 = acc3 = 0.f;
#pragma unroll 8
        for (int k = 0; k < H; k += 4) {
            float4 z0 = *(const float4*)&a1t[(rbase + 0) * H + k];
            float4 z1 = *(const float4*)&a1t[(rbase + 1) * H + k];
            float4 z2 = *(const float4*)&a1t[(rbase + 2) * H + k];
            float4 z3 = *(const float4*)&a1t[(rbase + 3) * H + k];
            const float w0 = W2s[(k + 0) * H + j], w1 = W2s[(k + 1) * H + j];
            const float w2 = W2s[(k + 2) * H + j], w3 = W2s[(k + 3) * H + j];
            acc0 += z0.x * w0 + z0.y * w1 + z0.z * w2 + z0.w * w3;
            acc1 += z1.x * w0 + z1.y * w1 + z1.z * w2 + z1.w * w3;
            acc2 += z2.x * w0 + z2.y * w1 + z2.z * w2 + z2.w * w3;
            acc3 += z3.x * w0 + z3.y * w1 + z3.z * w2 + z3.w * w3;
        }
        if (init) {
            if (rbase + 0 < nrows) out[(size_t)(r0 + rbase + 0) * H + j] = acc0 + b2j;
            if (rbase + 1 < nrows) out[(size_t)(r0 + rbase + 1) * H + j] = acc1 + b2j;
            if (rbase + 2 < nrows) out[(size_t)(r0 + rbase + 2) * H + j] = acc2 + b2j;
            if (rbase + 3 < nrows) out[(size_t)(r0 + rbase + 3) * H + j] = acc3 + b2j;
        } else {
            if (rbase + 0 < nrows) out[(size_t)(r0 + rbase + 0) * H + j] += acc0 + b2j;
            if (rbase + 1 < nrows) out[(size_t)(r0 + rbase + 1) * H + j] += acc1 + b2j;
            if (rbase + 2 < nrows) out[(size_t)(r0 + rbase + 2) * H + j] += acc2 + b2j;
            if (rbase + 3 < nrows) out[(size_t)(r0 + rbase + 3) * H + j] += acc3 + b2j;
        }
    }
}

// ---------------------------------------------------------------------------
// h = elu(out + h), elementwise over n4 float4s
__global__ __launch_bounds__(256) void k_combine(
    float* __restrict__ h, const float* __restrict__ outb, int n4)
{
    for (int i = blockIdx.x * blockDim.x + threadIdx.x; i < n4;
         i += gridDim.x * blockDim.x) {
        float4 o = ((const float4*)outb)[i];
        float4 hv = ((float4*)h)[i];
        float4 r;
        r.x = eluf(o.x + hv.x);
        r.y = eluf(o.y + hv.y);
        r.z = eluf(o.z + hv.z);
        r.w = eluf(o.w + hv.w);
        ((float4*)h)[i] = r;
    }
}

static inline int imin(int a, int b) { return a < b ? a : b; }

extern "C" void kernel_launch(void* const* d_in, const int* in_sizes, int n_in,
                              void* d_out, int out_size, void* d_ws, size_t ws_size,
                              hipStream_t stream) {
    const float* xin[3] = {(const float*)d_in[0], (const float*)d_in[1], (const float*)d_in[2]};
    const int* src[7]; const int* dst[7]; const float* ea[7]; int E[7];
    for (int r = 0; r < 7; ++r) {
        src[r] = (const int*)d_in[3 + 3 * r];
        dst[r] = (const int*)d_in[4 + 3 * r];
        ea[r]  = (const float*)d_in[5 + 3 * r];
        E[r]   = in_sizes[3 + 3 * r];
    }
    const float* linW[3] = {(const float*)d_in[24], (const float*)d_in[26], (const float*)d_in[28]};
    const float* linb[3] = {(const float*)d_in[25], (const float*)d_in[27], (const float*)d_in[29]};
    const float* eW  = (const float*)d_in[30];
    const float* ebp = (const float*)d_in[31];
    const float* W1  = (const float*)d_in[32];
    const float* b1  = (const float*)d_in[33];
    const float* g1  = (const float*)d_in[34];
    const float* be1 = (const float*)d_in[35];
    const float* W2  = (const float*)d_in[36];
    const float* b2  = (const float*)d_in[37];

    const int NSn[3]  = {in_sizes[0] / 64, in_sizes[1] / 64, in_sizes[2] / 64};
    const int NTOT = NSn[0] + NSn[1] + NSn[2];
    const int noff[3] = {0, NSn[0], NSn[0] + NSn[1]};

    float* h    = (float*)d_out;                  // node features live in d_out
    float* outb = (float*)d_ws;                   // per-layer output accumulator
    float* agg  = outb + (size_t)NTOT * H;        // one aggregation buffer (max type)

    hipFuncSetAttribute(reinterpret_cast<const void*>(k_mlp),
                        hipFuncAttributeMaxDynamicSharedMemorySize, MLP_SMEM);

    // initial per-type embedding
    for (int t = 0; t < 3; ++t) {
        int n = NSn[t];
        int grid = imin((n + 15) / 16, 2048);
        k_input_linear<<<grid, 128, 0, stream>>>(xin[t], linW[t], linb[t],
                                                 h + (size_t)noff[t] * H, n);
    }

    for (int l = 0; l < 3; ++l) {
        for (int r = 0; r < 7; ++r) {
            const int s = SRC_T_[r], t = DST_T_[r];
            const int nd = NSn[t];
            const int lr = l * 7 + r;
            hipMemsetAsync(agg, 0, (size_t)nd * H * sizeof(float), stream);
            int eg = imin((E[r] + 1) / 2, 8192);
            k_edge<<<eg, 256, 0, stream>>>(src[r], dst[r], ea[r],
                eW + (size_t)lr * 3 * H, ebp + (size_t)lr * H,
                h + (size_t)noff[s] * H, agg, E[r]);
            const int init = (r == 0 || r == 1 || r == 4) ? 1 : 0;
            int mg = imin((nd + 15) / 16, 256);
            k_mlp<<<mg, 512, MLP_SMEM, stream>>>(h + (size_t)noff[t] * H, agg,
                W1 + (size_t)lr * H * H, b1 + (size_t)lr * H,
                g1 + (size_t)lr * H, be1 + (size_t)lr * H,
                W2 + (size_t)lr * H * H, b2 + (size_t)lr * H,
                outb + (size_t)noff[t] * H, nd, init);
        }
        k_combine<<<2048, 256, 0, stream>>>(h, outb, NTOT * H / 4);
    }
}

// Round 2
// 2500.602 us; speedup vs baseline: 1.8319x; 1.8319x over previous
//
#include <hip/hip_runtime.h>
#include <math.h>

#define H 128

typedef __attribute__((ext_vector_type(8))) short short8;
typedef __attribute__((ext_vector_type(4))) float f32x4;

static const int SRC_T_[7] = {0, 0, 1, 1, 1, 2, 2};
static const int DST_T_[7] = {0, 1, 0, 1, 2, 1, 2};

__device__ __forceinline__ float eluf(float x) {
    return x > 0.f ? x : (__expf(x) - 1.f);
}
// round-to-nearest-even f32 -> bf16 bits
__device__ __forceinline__ unsigned short f2bf(float x) {
    union { float f; unsigned int u; } v; v.f = x;
    unsigned int r = v.u + 0x7fffu + ((v.u >> 16) & 1u);
    return (unsigned short)(r >> 16);
}

// ---------------------------------------------------------------------------
// h[t] = elu(x @ W + b); x:[n,64], W:[64,128]
__global__ __launch_bounds__(128) void k_input_linear(
    const float* __restrict__ x, const float* __restrict__ W,
    const float* __restrict__ b, float* __restrict__ h, int n)
{
    __shared__ float Ws[64 * H];
    __shared__ float xs[16 * 64];
    const int j = threadIdx.x;
    for (int i = j; i < 64 * H; i += 128) Ws[i] = W[i];
    const float bj = b[j];

    for (int r0 = blockIdx.x * 16; r0 < n; r0 += gridDim.x * 16) {
        const int nrows = min(16, n - r0);
        __syncthreads();
        for (int i = j; i < nrows * 64; i += 128) xs[i] = x[(size_t)r0 * 64 + i];
        __syncthreads();
        for (int i = 0; i < nrows; ++i) {
            float acc = bj;
#pragma unroll
            for (int k = 0; k < 64; k += 4) {
                float4 xv = *(const float4*)&xs[i * 64 + k];
                acc += xv.x * Ws[(k + 0) * H + j] + xv.y * Ws[(k + 1) * H + j]
                     + xv.z * Ws[(k + 2) * H + j] + xv.w * Ws[(k + 3) * H + j];
            }
            h[(size_t)(r0 + i) * H + j] = eluf(acc);
        }
    }
}

// ---------------------------------------------------------------------------
// msg = relu(h_src[src[e]] + ea[e] @ eW + eb); atomicAdd into agg[dst[e]].
__global__ __launch_bounds__(256) void k_edge(
    const int* __restrict__ src, const int* __restrict__ dst,
    const float* __restrict__ ea, const float* __restrict__ eW,
    const float* __restrict__ eb, const float* __restrict__ hsrc,
    float* __restrict__ agg, int E)
{
    const int j = threadIdx.x & 127;
    const int half = threadIdx.x >> 7;
    const float w0 = eW[j], w1 = eW[H + j], w2 = eW[2 * H + j], bj = eb[j];
    for (int e = blockIdx.x * 2 + half; e < E; e += gridDim.x * 2) {
        const int s = src[e], d = dst[e];
        const float a0 = ea[(size_t)e * 3 + 0];
        const float a1 = ea[(size_t)e * 3 + 1];
        const float a2 = ea[(size_t)e * 3 + 2];
        float m = hsrc[(size_t)s * H + j] + a0 * w0 + a1 * w1 + a2 * w2 + bj;
        m = fmaxf(m, 0.f);
        atomicAdd(&agg[(size_t)d * H + j], m);
    }
}

// ---------------------------------------------------------------------------
// MFMA MLP: z = hdst+agg (bf16); a1 = relu((z@W1+b1)*s+be) (bf16);
// out (+)= a1@W2 + b2  (fp32 accum throughout MFMA).
// 512 thr = 8 waves as 2(M)x4(N); wave = 64 rows x 32 cols; tile 128x128.
// LDS (128 KB): W1s | W2s | zt | a1t, each [128][128] bf16, XOR-swizzled:
//   elem index (row,col) -> row*128 + (col ^ ((row&7)<<3))   (byte ^ (row&7)<<4)
#define MLP_SMEM 131072
__global__ __launch_bounds__(512, 1) void k_mlp_mfma(
    const float* __restrict__ hdst, const float* __restrict__ agg,
    const float* __restrict__ W1g, const float* __restrict__ b1,
    const float* __restrict__ g1, const float* __restrict__ be1,
    const float* __restrict__ W2g, const float* __restrict__ b2,
    float* __restrict__ out, int n, int init)
{
    extern __shared__ unsigned short sm[];
    unsigned short* W1s = sm;            // W1^T swizzled [col][k]
    unsigned short* W2s = sm + 16384;
    unsigned short* zt  = sm + 32768;    // [row][k] swizzled
    unsigned short* a1t = sm + 49152;

    const int tid = threadIdx.x;
    const int lane = tid & 63;
    const int wave = tid >> 6;
    const int wr = wave >> 2;      // 0..1: 64-row block
    const int wc = wave & 3;       // 0..3: 32-col block
    const int l15 = lane & 15;
    const int lq  = lane >> 4;     // 0..3

    // weights: convert f32 -> bf16, transpose ([k][c] -> [c][k]) + swizzle, in LDS
    for (int i = tid; i < 16384; i += 512) {
        int c = i & 127, k = i >> 7;               // read row k coalesced
        int o = c * H + (k ^ ((c & 7) << 3));
        W1s[o] = f2bf(W1g[k * H + c]);
        W2s[o] = f2bf(W2g[k * H + c]);
    }

    const int c0 = wc * 32 + l15;  // this lane's base output column
    const float bn_inv = 0.99999500003749977f;  // 1/sqrt(1+1e-5)
    float b1c[2], sc[2], bec[2], b2c[2];
#pragma unroll
    for (int nf = 0; nf < 2; ++nf) {
        int c = c0 + nf * 16;
        b1c[nf] = b1[c]; sc[nf] = g1[c] * bn_inv; bec[nf] = be1[c]; b2c[nf] = b2[c];
    }
    __syncthreads();

    const f32x4 Z4 = {0.f, 0.f, 0.f, 0.f};

    for (int r0 = blockIdx.x * 128; r0 < n; r0 += gridDim.x * 128) {
        const int rows = min(128, n - r0);
        // stage z = hdst + agg -> bf16, swizzled
        for (int idx = tid; idx < rows * 32; idx += 512) {
            int row = idx >> 5, cg = (idx & 31) << 2;
            f32x4 hv = *(const f32x4*)&hdst[(size_t)(r0 + row) * H + cg];
            f32x4 av = *(const f32x4*)&agg[(size_t)(r0 + row) * H + cg];
            uint2 p;
            p.x = (unsigned int)f2bf(hv.x + av.x) | ((unsigned int)f2bf(hv.y + av.y) << 16);
            p.y = (unsigned int)f2bf(hv.z + av.z) | ((unsigned int)f2bf(hv.w + av.w) << 16);
            *(uint2*)&zt[row * H + (cg ^ ((row & 7) << 3))] = p;
        }
        __syncthreads();

        // ---- GEMM1: zt @ W1 ----
        f32x4 acc[4][2];
#pragma unroll
        for (int rb = 0; rb < 4; ++rb)
#pragma unroll
            for (int nf = 0; nf < 2; ++nf) acc[rb][nf] = Z4;
#pragma unroll
        for (int kc = 0; kc < 4; ++kc) {
            const int kb = kc * 32 + (lq << 3);
            short8 af[4], bfr[2];
#pragma unroll
            for (int rb = 0; rb < 4; ++rb) {
                int row = wr * 64 + rb * 16 + l15;
                af[rb] = *(const short8*)&zt[row * H + (kb ^ ((row & 7) << 3))];
            }
#pragma unroll
            for (int nf = 0; nf < 2; ++nf) {
                int trow = c0 + nf * 16;
                bfr[nf] = *(const short8*)&W1s[trow * H + (kb ^ ((trow & 7) << 3))];
            }
#pragma unroll
            for (int rb = 0; rb < 4; ++rb)
#pragma unroll
                for (int nf = 0; nf < 2; ++nf)
                    acc[rb][nf] = __builtin_amdgcn_mfma_f32_16x16x32_bf16(
                        af[rb], bfr[nf], acc[rb][nf], 0, 0, 0);
        }
        // epilogue1: BN+ReLU -> bf16 a1t (C/D layout: col=lane&15, row=lq*4+rg)
#pragma unroll
        for (int rb = 0; rb < 4; ++rb)
#pragma unroll
            for (int nf = 0; nf < 2; ++nf) {
                int col = c0 + nf * 16;
#pragma unroll
                for (int rg = 0; rg < 4; ++rg) {
                    int row = wr * 64 + rb * 16 + (lq << 2) + rg;
                    float v = fmaxf((acc[rb][nf][rg] + b1c[nf]) * sc[nf] + bec[nf], 0.f);
                    a1t[row * H + (col ^ ((row & 7) << 3))] = f2bf(v);
                }
            }
        __syncthreads();

        // ---- GEMM2: a1t @ W2 ----
#pragma unroll
        for (int rb = 0; rb < 4; ++rb)
#pragma unroll
            for (int nf = 0; nf < 2; ++nf) acc[rb][nf] = Z4;
#pragma unroll
        for (int kc = 0; kc < 4; ++kc) {
            const int kb = kc * 32 + (lq << 3);
            short8 af[4], bfr[2];
#pragma unroll
            for (int rb = 0; rb < 4; ++rb) {
                int row = wr * 64 + rb * 16 + l15;
                af[rb] = *(const short8*)&a1t[row * H + (kb ^ ((row & 7) << 3))];
            }
#pragma unroll
            for (int nf = 0; nf < 2; ++nf) {
                int trow = c0 + nf * 16;
                bfr[nf] = *(const short8*)&W2s[trow * H + (kb ^ ((trow & 7) << 3))];
            }
#pragma unroll
            for (int rb = 0; rb < 4; ++rb)
#pragma unroll
                for (int nf = 0; nf < 2; ++nf)
                    acc[rb][nf] = __builtin_amdgcn_mfma_f32_16x16x32_bf16(
                        af[rb], bfr[nf], acc[rb][nf], 0, 0, 0);
        }
        // epilogue2 -> out (global), guard tail rows
#pragma unroll
        for (int rb = 0; rb < 4; ++rb)
#pragma unroll
            for (int nf = 0; nf < 2; ++nf) {
                int col = c0 + nf * 16;
#pragma unroll
                for (int rg = 0; rg < 4; ++rg) {
                    int row = wr * 64 + rb * 16 + (lq << 2) + rg;
                    if (row < rows) {
                        size_t o = (size_t)(r0 + row) * H + col;
                        float v = acc[rb][nf][rg] + b2c[nf];
                        if (init) out[o] = v; else out[o] += v;
                    }
                }
            }
        // no barrier needed here: next iter touches zt only before its own barrier,
        // and zt is disjoint from a1t/W2s read in GEMM2.
    }
}

// ---------------------------------------------------------------------------
__global__ __launch_bounds__(256) void k_combine(
    float* __restrict__ h, const float* __restrict__ outb, int n4)
{
    for (int i = blockIdx.x * blockDim.x + threadIdx.x; i < n4;
         i += gridDim.x * blockDim.x) {
        float4 o = ((const float4*)outb)[i];
        float4 hv = ((float4*)h)[i];
        float4 r;
        r.x = eluf(o.x + hv.x);
        r.y = eluf(o.y + hv.y);
        r.z = eluf(o.z + hv.z);
        r.w = eluf(o.w + hv.w);
        ((float4*)h)[i] = r;
    }
}

static inline int imin(int a, int b) { return a < b ? a : b; }

extern "C" void kernel_launch(void* const* d_in, const int* in_sizes, int n_in,
                              void* d_out, int out_size, void* d_ws, size_t ws_size,
                              hipStream_t stream) {
    const float* xin[3] = {(const float*)d_in[0], (const float*)d_in[1], (const float*)d_in[2]};
    const int* src[7]; const int* dst[7]; const float* ea[7]; int E[7];
    for (int r = 0; r < 7; ++r) {
        src[r] = (const int*)d_in[3 + 3 * r];
        dst[r] = (const int*)d_in[4 + 3 * r];
        ea[r]  = (const float*)d_in[5 + 3 * r];
        E[r]   = in_sizes[3 + 3 * r];
    }
    const float* linW[3] = {(const float*)d_in[24], (const float*)d_in[26], (const float*)d_in[28]};
    const float* linb[3] = {(const float*)d_in[25], (const float*)d_in[27], (const float*)d_in[29]};
    const float* eW  = (const float*)d_in[30];
    const float* ebp = (const float*)d_in[31];
    const float* W1  = (const float*)d_in[32];
    const float* b1  = (const float*)d_in[33];
    const float* g1  = (const float*)d_in[34];
    const float* be1 = (const float*)d_in[35];
    const float* W2  = (const float*)d_in[36];
    const float* b2  = (const float*)d_in[37];

    const int NSn[3]  = {in_sizes[0] / 64, in_sizes[1] / 64, in_sizes[2] / 64};
    const int NTOT = NSn[0] + NSn[1] + NSn[2];
    const int noff[3] = {0, NSn[0], NSn[0] + NSn[1]};

    float* h    = (float*)d_out;                  // node features live in d_out
    float* outb = (float*)d_ws;                   // per-layer output accumulator
    float* agg  = outb + (size_t)NTOT * H;        // aggregation buffer (max type)

    hipFuncSetAttribute(reinterpret_cast<const void*>(k_mlp_mfma),
                        hipFuncAttributeMaxDynamicSharedMemorySize, MLP_SMEM);

    for (int t = 0; t < 3; ++t) {
        int n = NSn[t];
        int grid = imin((n + 15) / 16, 2048);
        k_input_linear<<<grid, 128, 0, stream>>>(xin[t], linW[t], linb[t],
                                                 h + (size_t)noff[t] * H, n);
    }

    for (int l = 0; l < 3; ++l) {
        for (int r = 0; r < 7; ++r) {
            const int s = SRC_T_[r], t = DST_T_[r];
            const int nd = NSn[t];
            const int lr = l * 7 + r;
            hipMemsetAsync(agg, 0, (size_t)nd * H * sizeof(float), stream);
            int eg = imin((E[r] + 1) / 2, 8192);
            k_edge<<<eg, 256, 0, stream>>>(src[r], dst[r], ea[r],
                eW + (size_t)lr * 3 * H, ebp + (size_t)lr * H,
                h + (size_t)noff[s] * H, agg, E[r]);
            const int init = (r == 0 || r == 1 || r == 4) ? 1 : 0;
            int mg = imin((nd + 127) / 128, 256);
            k_mlp_mfma<<<mg, 512, MLP_SMEM, stream>>>(h + (size_t)noff[t] * H, agg,
                W1 + (size_t)lr * H * H, b1 + (size_t)lr * H,
                g1 + (size_t)lr * H, be1 + (size_t)lr * H,
                W2 + (size_t)lr * H * H, b2 + (size_t)lr * H,
                outb + (size_t)noff[t] * H, nd, init);
        }
        k_combine<<<2048, 256, 0, stream>>>(h, outb, NTOT * H / 4);
    }
}

// Round 3
// 1944.609 us; speedup vs baseline: 2.3556x; 1.2859x over previous
//
#include <hip/hip_runtime.h>
#include <math.h>

#define H 128

typedef __attribute__((ext_vector_type(8))) short short8;
typedef __attribute__((ext_vector_type(4))) float f32x4;

static const int SRC_T_[7] = {0, 0, 1, 1, 1, 2, 2};
static const int DST_T_[7] = {0, 1, 0, 1, 2, 1, 2};
// per-relation MLP output mode: 0=init store, 1=accumulate, 2=final (fused combine)
static const int MODE_[7] = {0, 0, 2, 1, 0, 2, 2};

__device__ __forceinline__ float eluf(float x) {
    return x > 0.f ? x : (__expf(x) - 1.f);
}
__device__ __forceinline__ unsigned short f2bf(float x) {  // RNE f32->bf16
    union { float f; unsigned int u; } v; v.f = x;
    unsigned int r = v.u + 0x7fffu + ((v.u >> 16) & 1u);
    return (unsigned short)(r >> 16);
}
__device__ __forceinline__ float bf2f(unsigned short u) {
    union { unsigned int u; float f; } v; v.u = ((unsigned int)u) << 16;
    return v.f;
}

// ---------------------------------------------------------------------------
// h[t] = elu(x @ W + b); x:[n,64], W:[64,128]
__global__ __launch_bounds__(128) void k_input_linear(
    const float* __restrict__ x, const float* __restrict__ W,
    const float* __restrict__ b, float* __restrict__ h, int n)
{
    __shared__ float Ws[64 * H];
    __shared__ float xs[16 * 64];
    const int j = threadIdx.x;
    for (int i = j; i < 64 * H; i += 128) Ws[i] = W[i];
    const float bj = b[j];

    for (int r0 = blockIdx.x * 16; r0 < n; r0 += gridDim.x * 16) {
        const int nrows = min(16, n - r0);
        __syncthreads();
        for (int i = j; i < nrows * 64; i += 128) xs[i] = x[(size_t)r0 * 64 + i];
        __syncthreads();
        for (int i = 0; i < nrows; ++i) {
            float acc = bj;
#pragma unroll
            for (int k = 0; k < 64; k += 4) {
                float4 xv = *(const float4*)&xs[i * 64 + k];
                acc += xv.x * Ws[(k + 0) * H + j] + xv.y * Ws[(k + 1) * H + j]
                     + xv.z * Ws[(k + 2) * H + j] + xv.w * Ws[(k + 3) * H + j];
            }
            h[(size_t)(r0 + i) * H + j] = eluf(acc);
        }
    }
}

// --------------------------- CSR build -------------------------------------
__global__ __launch_bounds__(256) void k_hist(
    const int* __restrict__ dst, int* __restrict__ deg, int E)
{
    for (int e = blockIdx.x * 256 + threadIdx.x; e < E; e += gridDim.x * 256)
        atomicAdd(&deg[dst[e]], 1);
}

__global__ __launch_bounds__(256) void k_scan_partial(
    const int* __restrict__ deg, int* __restrict__ bsum, int n)
{
    __shared__ int s[256];
    const int tid = threadIdx.x;
    const int idx = blockIdx.x * 256 + tid;
    s[tid] = idx < n ? deg[idx] : 0;
    __syncthreads();
    for (int off = 128; off > 0; off >>= 1) {
        if (tid < off) s[tid] += s[tid + off];
        __syncthreads();
    }
    if (tid == 0) bsum[blockIdx.x] = s[0];
}

__global__ void k_scan_mid(int* bsum, int nb, int* ptr, int n)
{
    if (threadIdx.x == 0 && blockIdx.x == 0) {
        int run = 0;
        for (int i = 0; i < nb; ++i) { int t = bsum[i]; bsum[i] = run; run += t; }
        ptr[n] = run;
    }
}

__global__ __launch_bounds__(256) void k_scan_final(
    const int* __restrict__ deg, const int* __restrict__ bsum,
    int* __restrict__ ptr, int* __restrict__ cursor, int n)
{
    __shared__ int s[256];
    const int tid = threadIdx.x;
    const int idx = blockIdx.x * 256 + tid;
    const int v = idx < n ? deg[idx] : 0;
    s[tid] = v;
    __syncthreads();
    for (int off = 1; off < 256; off <<= 1) {
        int t = (tid >= off) ? s[tid - off] : 0;
        __syncthreads();
        s[tid] += t;
        __syncthreads();
    }
    if (idx < n) {
        int excl = s[tid] - v + bsum[blockIdx.x];
        ptr[idx] = excl;
        cursor[idx] = excl;
    }
}

__global__ __launch_bounds__(256) void k_scatter(
    const int* __restrict__ src, const int* __restrict__ dst,
    const float* __restrict__ ea, int* __restrict__ cursor,
    int* __restrict__ csr_src, float* __restrict__ csr_ea, int E)
{
    for (int e = blockIdx.x * 256 + threadIdx.x; e < E; e += gridDim.x * 256) {
        const int d = dst[e];
        const int pos = atomicAdd(&cursor[d], 1);
        csr_src[pos] = src[e];
        csr_ea[3 * pos + 0] = ea[(size_t)3 * e + 0];
        csr_ea[3 * pos + 1] = ea[(size_t)3 * e + 1];
        csr_ea[3 * pos + 2] = ea[(size_t)3 * e + 2];
    }
}

// ---------------------------------------------------------------------------
// Gather aggregation: agg[d] = sum_e relu(h_src[csr_src[e]] + ea@eW + eb), bf16.
// 64 lanes per node (2 cols each), 4 nodes per 256-thr block.
__global__ __launch_bounds__(256) void k_agg(
    const int* __restrict__ ptr, const int* __restrict__ csr_src,
    const float* __restrict__ csr_ea, const float* __restrict__ eW,
    const float* __restrict__ eb, const float* __restrict__ hsrc,
    unsigned short* __restrict__ agg, int nd)
{
    const int t2 = (threadIdx.x & 63) << 1;
    const int which = threadIdx.x >> 6;
    const float w00 = eW[t2],         w01 = eW[t2 + 1];
    const float w10 = eW[H + t2],     w11 = eW[H + t2 + 1];
    const float w20 = eW[2 * H + t2], w21 = eW[2 * H + t2 + 1];
    const float b0 = eb[t2], b1v = eb[t2 + 1];
    for (int d = blockIdx.x * 4 + which; d < nd; d += gridDim.x * 4) {
        const int p0 = ptr[d], p1 = ptr[d + 1];
        float acc0 = 0.f, acc1 = 0.f;
        for (int i = p0; i < p1; ++i) {
            const int s = csr_src[i];
            const float a0 = csr_ea[3 * i + 0];
            const float a1 = csr_ea[3 * i + 1];
            const float a2 = csr_ea[3 * i + 2];
            const float2 hv = *(const float2*)&hsrc[(size_t)s * H + t2];
            acc0 += fmaxf(hv.x + a0 * w00 + a1 * w10 + a2 * w20 + b0, 0.f);
            acc1 += fmaxf(hv.y + a0 * w01 + a1 * w11 + a2 * w21 + b1v, 0.f);
        }
        ((unsigned int*)agg)[d * 64 + (t2 >> 1)] =
            (unsigned int)f2bf(acc0) | ((unsigned int)f2bf(acc1) << 16);
    }
}

// ---------------------------------------------------------------------------
// MFMA MLP: z = hdst+agg (bf16); a1 = relu((z@W1+b1)*s+be);
// mode 0: out = a1@W2+b2; mode 1: out += ...; mode 2: hw = elu(out + ... + hdst)
#define MLP_SMEM 131072
__global__ __launch_bounds__(512, 1) void k_mlp_mfma(
    const float* hdst, const unsigned short* __restrict__ agg,
    const float* __restrict__ W1g, const float* __restrict__ b1,
    const float* __restrict__ g1, const float* __restrict__ be1,
    const float* __restrict__ W2g, const float* __restrict__ b2,
    float* out, float* hw, int n, int mode)
{
    extern __shared__ unsigned short sm[];
    unsigned short* W1s = sm;            // W^T swizzled [col][k]
    unsigned short* W2s = sm + 16384;
    unsigned short* zt  = sm + 32768;    // [row][k] swizzled
    unsigned short* a1t = sm + 49152;

    const int tid = threadIdx.x;
    const int lane = tid & 63;
    const int wave = tid >> 6;
    const int wr = wave >> 2;
    const int wc = wave & 3;
    const int l15 = lane & 15;
    const int lq  = lane >> 4;

    for (int i = tid; i < 16384; i += 512) {
        int c = i & 127, k = i >> 7;
        int o = c * H + (k ^ ((c & 7) << 3));
        W1s[o] = f2bf(W1g[k * H + c]);
        W2s[o] = f2bf(W2g[k * H + c]);
    }

    const int c0 = wc * 32 + l15;
    const float bn_inv = 0.99999500003749977f;
    float b1c[2], sc[2], bec[2], b2c[2];
#pragma unroll
    for (int nf = 0; nf < 2; ++nf) {
        int c = c0 + nf * 16;
        b1c[nf] = b1[c]; sc[nf] = g1[c] * bn_inv; bec[nf] = be1[c]; b2c[nf] = b2[c];
    }
    __syncthreads();

    const f32x4 Z4 = {0.f, 0.f, 0.f, 0.f};

    for (int r0 = blockIdx.x * 128; r0 < n; r0 += gridDim.x * 128) {
        const int rows = min(128, n - r0);
        for (int idx = tid; idx < rows * 32; idx += 512) {
            int row = idx >> 5, cg = (idx & 31) << 2;
            f32x4 hv = *(const f32x4*)&hdst[(size_t)(r0 + row) * H + cg];
            ushort4 av = *(const ushort4*)&agg[(size_t)(r0 + row) * H + cg];
            uint2 p;
            p.x = (unsigned int)f2bf(hv.x + bf2f(av.x))
                | ((unsigned int)f2bf(hv.y + bf2f(av.y)) << 16);
            p.y = (unsigned int)f2bf(hv.z + bf2f(av.z))
                | ((unsigned int)f2bf(hv.w + bf2f(av.w)) << 16);
            *(uint2*)&zt[row * H + (cg ^ ((row & 7) << 3))] = p;
        }
        __syncthreads();

        f32x4 acc[4][2];
#pragma unroll
        for (int rb = 0; rb < 4; ++rb)
#pragma unroll
            for (int nf = 0; nf < 2; ++nf) acc[rb][nf] = Z4;
#pragma unroll
        for (int kc = 0; kc < 4; ++kc) {
            const int kb = kc * 32 + (lq << 3);
            short8 af[4], bfr[2];
#pragma unroll
            for (int rb = 0; rb < 4; ++rb) {
                int row = wr * 64 + rb * 16 + l15;
                af[rb] = *(const short8*)&zt[row * H + (kb ^ ((row & 7) << 3))];
            }
#pragma unroll
            for (int nf = 0; nf < 2; ++nf) {
                int trow = c0 + nf * 16;
                bfr[nf] = *(const short8*)&W1s[trow * H + (kb ^ ((trow & 7) << 3))];
            }
#pragma unroll
            for (int rb = 0; rb < 4; ++rb)
#pragma unroll
                for (int nf = 0; nf < 2; ++nf)
                    acc[rb][nf] = __builtin_amdgcn_mfma_f32_16x16x32_bf16(
                        af[rb], bfr[nf], acc[rb][nf], 0, 0, 0);
        }
#pragma unroll
        for (int rb = 0; rb < 4; ++rb)
#pragma unroll
            for (int nf = 0; nf < 2; ++nf) {
                int col = c0 + nf * 16;
#pragma unroll
                for (int rg = 0; rg < 4; ++rg) {
                    int row = wr * 64 + rb * 16 + (lq << 2) + rg;
                    float v = fmaxf((acc[rb][nf][rg] + b1c[nf]) * sc[nf] + bec[nf], 0.f);
                    a1t[row * H + (col ^ ((row & 7) << 3))] = f2bf(v);
                }
            }
        __syncthreads();

#pragma unroll
        for (int rb = 0; rb < 4; ++rb)
#pragma unroll
            for (int nf = 0; nf < 2; ++nf) acc[rb][nf] = Z4;
#pragma unroll
        for (int kc = 0; kc < 4; ++kc) {
            const int kb = kc * 32 + (lq << 3);
            short8 af[4], bfr[2];
#pragma unroll
            for (int rb = 0; rb < 4; ++rb) {
                int row = wr * 64 + rb * 16 + l15;
                af[rb] = *(const short8*)&a1t[row * H + (kb ^ ((row & 7) << 3))];
            }
#pragma unroll
            for (int nf = 0; nf < 2; ++nf) {
                int trow = c0 + nf * 16;
                bfr[nf] = *(const short8*)&W2s[trow * H + (kb ^ ((trow & 7) << 3))];
            }
#pragma unroll
            for (int rb = 0; rb < 4; ++rb)
#pragma unroll
                for (int nf = 0; nf < 2; ++nf)
                    acc[rb][nf] = __builtin_amdgcn_mfma_f32_16x16x32_bf16(
                        af[rb], bfr[nf], acc[rb][nf], 0, 0, 0);
        }
#pragma unroll
        for (int rb = 0; rb < 4; ++rb)
#pragma unroll
            for (int nf = 0; nf < 2; ++nf) {
                int col = c0 + nf * 16;
#pragma unroll
                for (int rg = 0; rg < 4; ++rg) {
                    int row = wr * 64 + rb * 16 + (lq << 2) + rg;
                    if (row < rows) {
                        size_t o = (size_t)(r0 + row) * H + col;
                        float v = acc[rb][nf][rg] + b2c[nf];
                        if (mode == 0) out[o] = v;
                        else if (mode == 1) out[o] += v;
                        else hw[o] = eluf(out[o] + v + hdst[o]);
                    }
                }
            }
    }
}

static inline int imin(int a, int b) { return a < b ? a : b; }
static inline size_t alignup(size_t x) { return (x + 255) & ~(size_t)255; }

extern "C" void kernel_launch(void* const* d_in, const int* in_sizes, int n_in,
                              void* d_out, int out_size, void* d_ws, size_t ws_size,
                              hipStream_t stream) {
    const float* xin[3] = {(const float*)d_in[0], (const float*)d_in[1], (const float*)d_in[2]};
    const int* src[7]; const int* dst[7]; const float* ea[7]; int E[7];
    for (int r = 0; r < 7; ++r) {
        src[r] = (const int*)d_in[3 + 3 * r];
        dst[r] = (const int*)d_in[4 + 3 * r];
        ea[r]  = (const float*)d_in[5 + 3 * r];
        E[r]   = in_sizes[3 + 3 * r];
    }
    const float* linW[3] = {(const float*)d_in[24], (const float*)d_in[26], (const float*)d_in[28]};
    const float* linb[3] = {(const float*)d_in[25], (const float*)d_in[27], (const float*)d_in[29]};
    const float* eW  = (const float*)d_in[30];
    const float* ebp = (const float*)d_in[31];
    const float* W1  = (const float*)d_in[32];
    const float* b1  = (const float*)d_in[33];
    const float* g1  = (const float*)d_in[34];
    const float* be1 = (const float*)d_in[35];
    const float* W2  = (const float*)d_in[36];
    const float* b2  = (const float*)d_in[37];

    const int NSn[3]  = {in_sizes[0] / 64, in_sizes[1] / 64, in_sizes[2] / 64};
    const int NTOT = NSn[0] + NSn[1] + NSn[2];
    const int noff[3] = {0, NSn[0], NSn[0] + NSn[1]};
    int maxn = NSn[0]; if (NSn[1] > maxn) maxn = NSn[1]; if (NSn[2] > maxn) maxn = NSn[2];
    int Etot = 0; for (int r = 0; r < 7; ++r) Etot += E[r];

    float* h = (float*)d_out;

    // workspace carve-up
    char* wsb = (char*)d_ws;
    size_t off = 0;
    float* outb = (float*)(wsb + off);          off = alignup(off + (size_t)NTOT * H * 4);
    unsigned short* agg = (unsigned short*)(wsb + off); off = alignup(off + (size_t)maxn * H * 2);
    int* deg    = (int*)(wsb + off);            off = alignup(off + (size_t)maxn * 4);
    int* cursor = (int*)(wsb + off);            off = alignup(off + (size_t)maxn * 4);
    int* bsum   = (int*)(wsb + off);            off = alignup(off + 4096);
    int* ptrs[7]; int* csrs[7]; float* ceas[7];
    for (int r = 0; r < 7; ++r) {
        int nd = NSn[DST_T_[r]];
        ptrs[r] = (int*)(wsb + off); off = alignup(off + (size_t)(nd + 1) * 4);
    }
    for (int r = 0; r < 7; ++r) {
        csrs[r] = (int*)(wsb + off); off = alignup(off + (size_t)E[r] * 4);
    }
    for (int r = 0; r < 7; ++r) {
        ceas[r] = (float*)(wsb + off); off = alignup(off + (size_t)E[r] * 12);
    }

    hipFuncSetAttribute(reinterpret_cast<const void*>(k_mlp_mfma),
                        hipFuncAttributeMaxDynamicSharedMemorySize, MLP_SMEM);

    // ---- CSR build (once per call, reused by all 3 layers) ----
    for (int r = 0; r < 7; ++r) {
        const int nd = NSn[DST_T_[r]];
        const int nb = (nd + 255) / 256;
        hipMemsetAsync(deg, 0, (size_t)nd * 4, stream);
        k_hist<<<imin((E[r] + 255) / 256, 2048), 256, 0, stream>>>(dst[r], deg, E[r]);
        k_scan_partial<<<nb, 256, 0, stream>>>(deg, bsum, nd);
        k_scan_mid<<<1, 64, 0, stream>>>(bsum, nb, ptrs[r], nd);
        k_scan_final<<<nb, 256, 0, stream>>>(deg, bsum, ptrs[r], cursor, nd);
        k_scatter<<<imin((E[r] + 255) / 256, 2048), 256, 0, stream>>>(
            src[r], dst[r], ea[r], cursor, csrs[r], ceas[r], E[r]);
    }

    // ---- input embeddings ----
    for (int t = 0; t < 3; ++t) {
        int n = NSn[t];
        k_input_linear<<<imin((n + 15) / 16, 2048), 128, 0, stream>>>(
            xin[t], linW[t], linb[t], h + (size_t)noff[t] * H, n);
    }

    // ---- layers ----
    for (int l = 0; l < 3; ++l) {
        for (int r = 0; r < 7; ++r) {
            const int s = SRC_T_[r], t = DST_T_[r];
            const int nd = NSn[t];
            const int lr = l * 7 + r;
            k_agg<<<(nd + 3) / 4, 256, 0, stream>>>(
                ptrs[r], csrs[r], ceas[r],
                eW + (size_t)lr * 3 * H, ebp + (size_t)lr * H,
                h + (size_t)noff[s] * H, agg, nd);
            k_mlp_mfma<<<imin((nd + 127) / 128, 256), 512, MLP_SMEM, stream>>>(
                h + (size_t)noff[t] * H, agg,
                W1 + (size_t)lr * H * H, b1 + (size_t)lr * H,
                g1 + (size_t)lr * H, be1 + (size_t)lr * H,
                W2 + (size_t)lr * H * H, b2 + (size_t)lr * H,
                outb + (size_t)noff[t] * H, h + (size_t)noff[t] * H, nd, MODE_[r]);
        }
    }
}

// Round 4
// 1941.455 us; speedup vs baseline: 2.3595x; 1.0016x over previous
//
#include <hip/hip_runtime.h>
#include <math.h>

#define H 128

typedef __attribute__((ext_vector_type(8))) short short8;
typedef __attribute__((ext_vector_type(4))) float f32x4;

static const int SRC_T_[7] = {0, 0, 1, 1, 1, 2, 2};
static const int DST_T_[7] = {0, 1, 0, 1, 2, 1, 2};

__device__ __forceinline__ float eluf(float x) {
    return x > 0.f ? x : (__expf(x) - 1.f);
}
__device__ __forceinline__ unsigned short f2bf(float x) {  // RNE f32->bf16
    union { float f; unsigned int u; } v; v.f = x;
    unsigned int r = v.u + 0x7fffu + ((v.u >> 16) & 1u);
    return (unsigned short)(r >> 16);
}
__device__ __forceinline__ float bf2f(unsigned short u) {
    union { unsigned int u; float f; } v; v.u = ((unsigned int)u) << 16;
    return v.f;
}

// ---------------------------------------------------------------------------
// h[t] = elu(x @ W + b); x:[n,64], W:[64,128]
__global__ __launch_bounds__(128) void k_input_linear(
    const float* __restrict__ x, const float* __restrict__ W,
    const float* __restrict__ b, float* __restrict__ h, int n)
{
    __shared__ float Ws[64 * H];
    __shared__ float xs[16 * 64];
    const int j = threadIdx.x;
    for (int i = j; i < 64 * H; i += 128) Ws[i] = W[i];
    const float bj = b[j];

    for (int r0 = blockIdx.x * 16; r0 < n; r0 += gridDim.x * 16) {
        const int nrows = min(16, n - r0);
        __syncthreads();
        for (int i = j; i < nrows * 64; i += 128) xs[i] = x[(size_t)r0 * 64 + i];
        __syncthreads();
        for (int i = 0; i < nrows; ++i) {
            float acc = bj;
#pragma unroll
            for (int k = 0; k < 64; k += 4) {
                float4 xv = *(const float4*)&xs[i * 64 + k];
                acc += xv.x * Ws[(k + 0) * H + j] + xv.y * Ws[(k + 1) * H + j]
                     + xv.z * Ws[(k + 2) * H + j] + xv.w * Ws[(k + 3) * H + j];
            }
            h[(size_t)(r0 + i) * H + j] = eluf(acc);
        }
    }
}

// --------------------------- CSR build -------------------------------------
__global__ __launch_bounds__(256) void k_hist(
    const int* __restrict__ dst, int* __restrict__ deg, int E)
{
    for (int e = blockIdx.x * 256 + threadIdx.x; e < E; e += gridDim.x * 256)
        atomicAdd(&deg[dst[e]], 1);
}

__global__ __launch_bounds__(256) void k_scan_partial(
    const int* __restrict__ deg, int* __restrict__ bsum, int n)
{
    __shared__ int s[256];
    const int tid = threadIdx.x;
    const int idx = blockIdx.x * 256 + tid;
    s[tid] = idx < n ? deg[idx] : 0;
    __syncthreads();
    for (int off = 128; off > 0; off >>= 1) {
        if (tid < off) s[tid] += s[tid + off];
        __syncthreads();
    }
    if (tid == 0) bsum[blockIdx.x] = s[0];
}

__global__ void k_scan_mid(int* bsum, int nb, int* ptr, int n)
{
    if (threadIdx.x == 0 && blockIdx.x == 0) {
        int run = 0;
        for (int i = 0; i < nb; ++i) { int t = bsum[i]; bsum[i] = run; run += t; }
        ptr[n] = run;
    }
}

__global__ __launch_bounds__(256) void k_scan_final(
    const int* __restrict__ deg, const int* __restrict__ bsum,
    int* __restrict__ ptr, int* __restrict__ cursor, int n)
{
    __shared__ int s[256];
    const int tid = threadIdx.x;
    const int idx = blockIdx.x * 256 + tid;
    const int v = idx < n ? deg[idx] : 0;
    s[tid] = v;
    __syncthreads();
    for (int off = 1; off < 256; off <<= 1) {
        int t = (tid >= off) ? s[tid - off] : 0;
        __syncthreads();
        s[tid] += t;
        __syncthreads();
    }
    if (idx < n) {
        int excl = s[tid] - v + bsum[blockIdx.x];
        ptr[idx] = excl;
        cursor[idx] = excl;
    }
}

__global__ __launch_bounds__(256) void k_scatter(
    const int* __restrict__ src, const int* __restrict__ dst,
    const float* __restrict__ ea, int* __restrict__ cursor,
    int* __restrict__ csr_src, float* __restrict__ csr_ea, int E)
{
    for (int e = blockIdx.x * 256 + threadIdx.x; e < E; e += gridDim.x * 256) {
        const int d = dst[e];
        const int pos = atomicAdd(&cursor[d], 1);
        csr_src[pos] = src[e];
        csr_ea[3 * pos + 0] = ea[(size_t)3 * e + 0];
        csr_ea[3 * pos + 1] = ea[(size_t)3 * e + 1];
        csr_ea[3 * pos + 2] = ea[(size_t)3 * e + 2];
    }
}

// ---------------------------------------------------------------------------
// Weight prep: W1,W2 [21][128k][128c] f32 -> wp [21][2][128c][128k] bf16
__global__ __launch_bounds__(256) void k_wprep(
    const float* __restrict__ W1, const float* __restrict__ W2,
    unsigned short* __restrict__ wp, int total)
{
    for (int i = blockIdx.x * 256 + threadIdx.x; i < total; i += gridDim.x * 256) {
        int lr = i >> 14, rem = i & 16383;
        int c = rem >> 7, k = rem & 127;
        wp[(size_t)(lr * 2 + 0) * 16384 + rem] = f2bf(W1[(size_t)lr * 16384 + k * H + c]);
        wp[(size_t)(lr * 2 + 1) * 16384 + rem] = f2bf(W2[(size_t)lr * 16384 + k * H + c]);
    }
}

// ---------------------------------------------------------------------------
// Gather aggregation: agg[d] = sum_e relu(h_src[csr_src[e]] + ea@eW + eb), bf16.
__global__ __launch_bounds__(256) void k_agg(
    const int* __restrict__ ptr, const int* __restrict__ csr_src,
    const float* __restrict__ csr_ea, const float* __restrict__ eW,
    const float* __restrict__ eb, const float* __restrict__ hsrc,
    unsigned short* __restrict__ agg, int nd)
{
    const int t2 = (threadIdx.x & 63) << 1;
    const int which = threadIdx.x >> 6;
    const float w00 = eW[t2],         w01 = eW[t2 + 1];
    const float w10 = eW[H + t2],     w11 = eW[H + t2 + 1];
    const float w20 = eW[2 * H + t2], w21 = eW[2 * H + t2 + 1];
    const float b0 = eb[t2], b1v = eb[t2 + 1];
    for (int d = blockIdx.x * 4 + which; d < nd; d += gridDim.x * 4) {
        const int p0 = ptr[d], p1 = ptr[d + 1];
        float acc0 = 0.f, acc1 = 0.f;
        for (int i = p0; i < p1; ++i) {
            const int s = csr_src[i];
            const float a0 = csr_ea[3 * i + 0];
            const float a1 = csr_ea[3 * i + 1];
            const float a2 = csr_ea[3 * i + 2];
            const float2 hv = *(const float2*)&hsrc[(size_t)s * H + t2];
            acc0 += fmaxf(hv.x + a0 * w00 + a1 * w10 + a2 * w20 + b0, 0.f);
            acc1 += fmaxf(hv.y + a0 * w01 + a1 * w11 + a2 * w21 + b1v, 0.f);
        }
        ((unsigned int*)agg)[d * 64 + (t2 >> 1)] =
            (unsigned int)f2bf(acc0) | ((unsigned int)f2bf(acc1) << 16);
    }
}

// ---------------------------------------------------------------------------
// Fused multi-relation MFMA MLP for one dst type:
//   h = elu( sum_rel (relu((hdst+agg_rel)@W1*bn+..)@W2 + b2) + hdst )
// One 128-row tile per block. LDS 64 KB (zt + a1t) -> 2 blocks/CU.
// Weights held in registers (B-fragments) per relation; acc2 chains over rels.
template<int NREL>
__global__ __launch_bounds__(512, 4) void k_mlp_fused(
    const float* __restrict__ hdst, float* __restrict__ hw,
    const unsigned short* __restrict__ wprep,
    const float* __restrict__ b1g, const float* __restrict__ g1g,
    const float* __restrict__ be1g, const float* __restrict__ b2g,
    const unsigned short* __restrict__ aggA,
    const unsigned short* __restrict__ aggB,
    const unsigned short* __restrict__ aggC,
    int lrA, int lrB, int lrC, int n)
{
    __shared__ unsigned short zt[128 * H];   // 32 KB, XOR-swizzled
    __shared__ unsigned short a1t[128 * H];  // 32 KB

    const unsigned short* aggp[3] = {aggA, aggB, aggC};
    const int lrv[3] = {lrA, lrB, lrC};

    const int tid = threadIdx.x;
    const int lane = tid & 63;
    const int wave = tid >> 6;
    const int wr = wave >> 2;      // 0..1
    const int wc = wave & 3;       // 0..3
    const int l15 = lane & 15;
    const int lq  = lane >> 4;
    const int c0 = wc * 32 + l15;

    const int r0 = blockIdx.x * 128;
    const int rows = min(128, n - r0);

    // per-relation epilogue scalars
    const float bn_inv = 0.99999500003749977f;
    float b1c[NREL][2], sc[NREL][2], bec[NREL][2], b2sum[2] = {0.f, 0.f};
#pragma unroll
    for (int rl = 0; rl < NREL; ++rl)
#pragma unroll
        for (int nf = 0; nf < 2; ++nf) {
            const int c = lrv[rl] * H + c0 + nf * 16;
            b1c[rl][nf] = b1g[c]; sc[rl][nf] = g1g[c] * bn_inv;
            bec[rl][nf] = be1g[c]; b2sum[nf] += b2g[c];
        }

    const f32x4 Z4 = {0.f, 0.f, 0.f, 0.f};
    f32x4 acc2[4][2];
#pragma unroll
    for (int rb = 0; rb < 4; ++rb)
#pragma unroll
        for (int nf = 0; nf < 2; ++nf) acc2[rb][nf] = Z4;

#pragma unroll
    for (int rl = 0; rl < NREL; ++rl) {
        // ---- weight fragments for this relation (global bf16 -> regs) ----
        const unsigned short* wp = wprep + (size_t)lrv[rl] * 32768;
        short8 w1f[2][4], w2f[2][4];
#pragma unroll
        for (int nf = 0; nf < 2; ++nf) {
            const int c = c0 + nf * 16;
#pragma unroll
            for (int kc = 0; kc < 4; ++kc) {
                w1f[nf][kc] = *(const short8*)&wp[c * H + kc * 32 + (lq << 3)];
                w2f[nf][kc] = *(const short8*)&wp[16384 + c * H + kc * 32 + (lq << 3)];
            }
        }
        // ---- stage z = hdst + agg_rel (bf16, swizzled) ----
        const unsigned short* ag = aggp[rl];
        if (rows == 128) {
            f32x4 hv[8]; ushort4 av[8];
#pragma unroll
            for (int it = 0; it < 8; ++it) {
                const int idx = tid + it * 512;
                const int row = idx >> 5, cg = (idx & 31) << 2;
                hv[it] = *(const f32x4*)&hdst[(size_t)(r0 + row) * H + cg];
                av[it] = *(const ushort4*)&ag[(size_t)(r0 + row) * H + cg];
            }
#pragma unroll
            for (int it = 0; it < 8; ++it) {
                const int idx = tid + it * 512;
                const int row = idx >> 5, cg = (idx & 31) << 2;
                uint2 p;
                p.x = (unsigned int)f2bf(hv[it].x + bf2f(av[it].x))
                    | ((unsigned int)f2bf(hv[it].y + bf2f(av[it].y)) << 16);
                p.y = (unsigned int)f2bf(hv[it].z + bf2f(av[it].z))
                    | ((unsigned int)f2bf(hv[it].w + bf2f(av[it].w)) << 16);
                *(uint2*)&zt[row * H + (cg ^ ((row & 7) << 3))] = p;
            }
        } else {
            for (int idx = tid; idx < rows * 32; idx += 512) {
                const int row = idx >> 5, cg = (idx & 31) << 2;
                f32x4 hv = *(const f32x4*)&hdst[(size_t)(r0 + row) * H + cg];
                ushort4 av = *(const ushort4*)&ag[(size_t)(r0 + row) * H + cg];
                uint2 p;
                p.x = (unsigned int)f2bf(hv.x + bf2f(av.x))
                    | ((unsigned int)f2bf(hv.y + bf2f(av.y)) << 16);
                p.y = (unsigned int)f2bf(hv.z + bf2f(av.z))
                    | ((unsigned int)f2bf(hv.w + bf2f(av.w)) << 16);
                *(uint2*)&zt[row * H + (cg ^ ((row & 7) << 3))] = p;
            }
        }
        __syncthreads();  // A: zt ready

        // ---- GEMM1: zt @ W1 ----
        f32x4 acc1[4][2];
#pragma unroll
        for (int rb = 0; rb < 4; ++rb)
#pragma unroll
            for (int nf = 0; nf < 2; ++nf) acc1[rb][nf] = Z4;
#pragma unroll
        for (int kc = 0; kc < 4; ++kc) {
            const int kb = kc * 32 + (lq << 3);
            short8 af[4];
#pragma unroll
            for (int rb = 0; rb < 4; ++rb) {
                const int row = wr * 64 + rb * 16 + l15;
                af[rb] = *(const short8*)&zt[row * H + (kb ^ ((row & 7) << 3))];
            }
#pragma unroll
            for (int rb = 0; rb < 4; ++rb)
#pragma unroll
                for (int nf = 0; nf < 2; ++nf)
                    acc1[rb][nf] = __builtin_amdgcn_mfma_f32_16x16x32_bf16(
                        af[rb], w1f[nf][kc], acc1[rb][nf], 0, 0, 0);
        }
        // epilogue1: BN+ReLU -> a1t
#pragma unroll
        for (int rb = 0; rb < 4; ++rb)
#pragma unroll
            for (int nf = 0; nf < 2; ++nf) {
                const int col = c0 + nf * 16;
#pragma unroll
                for (int rg = 0; rg < 4; ++rg) {
                    const int row = wr * 64 + rb * 16 + (lq << 2) + rg;
                    float v = fmaxf((acc1[rb][nf][rg] + b1c[rl][nf]) * sc[rl][nf]
                                    + bec[rl][nf], 0.f);
                    a1t[row * H + (col ^ ((row & 7) << 3))] = f2bf(v);
                }
            }
        __syncthreads();  // B: a1t ready

        // ---- GEMM2: a1t @ W2, C chained in acc2 ----
#pragma unroll
        for (int kc = 0; kc < 4; ++kc) {
            const int kb = kc * 32 + (lq << 3);
            short8 af[4];
#pragma unroll
            for (int rb = 0; rb < 4; ++rb) {
                const int row = wr * 64 + rb * 16 + l15;
                af[rb] = *(const short8*)&a1t[row * H + (kb ^ ((row & 7) << 3))];
            }
#pragma unroll
            for (int rb = 0; rb < 4; ++rb)
#pragma unroll
                for (int nf = 0; nf < 2; ++nf)
                    acc2[rb][nf] = __builtin_amdgcn_mfma_f32_16x16x32_bf16(
                        af[rb], w2f[nf][kc], acc2[rb][nf], 0, 0, 0);
        }
    }

    // ---- final epilogue: h = elu(acc2 + sum(b2) + hdst) ----
#pragma unroll
    for (int rb = 0; rb < 4; ++rb)
#pragma unroll
        for (int nf = 0; nf < 2; ++nf) {
            const int col = c0 + nf * 16;
#pragma unroll
            for (int rg = 0; rg < 4; ++rg) {
                const int row = wr * 64 + rb * 16 + (lq << 2) + rg;
                if (row < rows) {
                    const size_t o = (size_t)(r0 + row) * H + col;
                    hw[o] = eluf(acc2[rb][nf][rg] + b2sum[nf] + hdst[o]);
                }
            }
        }
}

static inline int imin(int a, int b) { return a < b ? a : b; }
static inline size_t alignup(size_t x) { return (x + 255) & ~(size_t)255; }

extern "C" void kernel_launch(void* const* d_in, const int* in_sizes, int n_in,
                              void* d_out, int out_size, void* d_ws, size_t ws_size,
                              hipStream_t stream) {
    const float* xin[3] = {(const float*)d_in[0], (const float*)d_in[1], (const float*)d_in[2]};
    const int* src[7]; const int* dst[7]; const float* ea[7]; int E[7];
    for (int r = 0; r < 7; ++r) {
        src[r] = (const int*)d_in[3 + 3 * r];
        dst[r] = (const int*)d_in[4 + 3 * r];
        ea[r]  = (const float*)d_in[5 + 3 * r];
        E[r]   = in_sizes[3 + 3 * r];
    }
    const float* linW[3] = {(const float*)d_in[24], (const float*)d_in[26], (const float*)d_in[28]};
    const float* linb[3] = {(const float*)d_in[25], (const float*)d_in[27], (const float*)d_in[29]};
    const float* eW  = (const float*)d_in[30];
    const float* ebp = (const float*)d_in[31];
    const float* W1  = (const float*)d_in[32];
    const float* b1  = (const float*)d_in[33];
    const float* g1  = (const float*)d_in[34];
    const float* be1 = (const float*)d_in[35];
    const float* W2  = (const float*)d_in[36];
    const float* b2  = (const float*)d_in[37];

    const int NSn[3]  = {in_sizes[0] / 64, in_sizes[1] / 64, in_sizes[2] / 64};
    const int noff[3] = {0, NSn[0], NSn[0] + NSn[1]};
    int maxn = NSn[0]; if (NSn[1] > maxn) maxn = NSn[1]; if (NSn[2] > maxn) maxn = NSn[2];

    float* h = (float*)d_out;

    // workspace carve-up
    char* wsb = (char*)d_ws;
    size_t off = 0;
    unsigned short* aggb[7];
    for (int r = 0; r < 7; ++r) {
        int nd = NSn[DST_T_[r]];
        aggb[r] = (unsigned short*)(wsb + off); off = alignup(off + (size_t)nd * H * 2);
    }
    unsigned short* wprep = (unsigned short*)(wsb + off); off = alignup(off + (size_t)21 * 2 * 16384 * 2);
    int* deg    = (int*)(wsb + off); off = alignup(off + (size_t)maxn * 4);
    int* cursor = (int*)(wsb + off); off = alignup(off + (size_t)maxn * 4);
    int* bsum   = (int*)(wsb + off); off = alignup(off + 4096);
    int* ptrs[7]; int* csrs[7]; float* ceas[7];
    for (int r = 0; r < 7; ++r) {
        int nd = NSn[DST_T_[r]];
        ptrs[r] = (int*)(wsb + off); off = alignup(off + (size_t)(nd + 1) * 4);
    }
    for (int r = 0; r < 7; ++r) {
        csrs[r] = (int*)(wsb + off); off = alignup(off + (size_t)E[r] * 4);
    }
    for (int r = 0; r < 7; ++r) {
        ceas[r] = (float*)(wsb + off); off = alignup(off + (size_t)E[r] * 12);
    }

    // ---- CSR build + weight prep ----
    for (int r = 0; r < 7; ++r) {
        const int nd = NSn[DST_T_[r]];
        const int nb = (nd + 255) / 256;
        hipMemsetAsync(deg, 0, (size_t)nd * 4, stream);
        k_hist<<<imin((E[r] + 255) / 256, 2048), 256, 0, stream>>>(dst[r], deg, E[r]);
        k_scan_partial<<<nb, 256, 0, stream>>>(deg, bsum, nd);
        k_scan_mid<<<1, 64, 0, stream>>>(bsum, nb, ptrs[r], nd);
        k_scan_final<<<nb, 256, 0, stream>>>(deg, bsum, ptrs[r], cursor, nd);
        k_scatter<<<imin((E[r] + 255) / 256, 2048), 256, 0, stream>>>(
            src[r], dst[r], ea[r], cursor, csrs[r], ceas[r], E[r]);
    }
    k_wprep<<<1344, 256, 0, stream>>>(W1, W2, wprep, 21 * 16384);

    // ---- input embeddings ----
    for (int t = 0; t < 3; ++t) {
        int n = NSn[t];
        k_input_linear<<<imin((n + 15) / 16, 2048), 128, 0, stream>>>(
            xin[t], linW[t], linb[t], h + (size_t)noff[t] * H, n);
    }

    // ---- layers ----
    for (int l = 0; l < 3; ++l) {
        for (int r = 0; r < 7; ++r) {
            const int s = SRC_T_[r];
            const int nd = NSn[DST_T_[r]];
            const int lr = l * 7 + r;
            k_agg<<<(nd + 3) / 4, 256, 0, stream>>>(
                ptrs[r], csrs[r], ceas[r],
                eW + (size_t)lr * 3 * H, ebp + (size_t)lr * H,
                h + (size_t)noff[s] * H, aggb[r], nd);
        }
        // dst type 0: relations {0,2}
        k_mlp_fused<2><<<(NSn[0] + 127) / 128, 512, 0, stream>>>(
            h + (size_t)noff[0] * H, h + (size_t)noff[0] * H, wprep,
            b1, g1, be1, b2, aggb[0], aggb[2], aggb[0],
            l * 7 + 0, l * 7 + 2, 0, NSn[0]);
        // dst type 1: relations {1,3,5}
        k_mlp_fused<3><<<(NSn[1] + 127) / 128, 512, 0, stream>>>(
            h + (size_t)noff[1] * H, h + (size_t)noff[1] * H, wprep,
            b1, g1, be1, b2, aggb[1], aggb[3], aggb[5],
            l * 7 + 1, l * 7 + 3, l * 7 + 5, NSn[1]);
        // dst type 2: relations {4,6}
        k_mlp_fused<2><<<(NSn[2] + 127) / 128, 512, 0, stream>>>(
            h + (size_t)noff[2] * H, h + (size_t)noff[2] * H, wprep,
            b1, g1, be1, b2, aggb[4], aggb[6], aggb[4],
            l * 7 + 4, l * 7 + 6, 0, NSn[2]);
    }
}

// Round 5
// 1618.399 us; speedup vs baseline: 2.8305x; 1.1996x over previous
//
#include <hip/hip_runtime.h>
#include <math.h>

#define H 128

typedef __attribute__((ext_vector_type(8))) short short8;
typedef __attribute__((ext_vector_type(4))) float f32x4;

static const int SRC_T_[7] = {0, 0, 1, 1, 1, 2, 2};
static const int DST_T_[7] = {0, 1, 0, 1, 2, 1, 2};

__device__ __forceinline__ float eluf(float x) {
    return x > 0.f ? x : (__expf(x) - 1.f);
}
__device__ __forceinline__ unsigned short f2bf(float x) {  // RNE f32->bf16
    union { float f; unsigned int u; } v; v.f = x;
    unsigned int r = v.u + 0x7fffu + ((v.u >> 16) & 1u);
    return (unsigned short)(r >> 16);
}
__device__ __forceinline__ float bf2f(unsigned int u) {
    union { unsigned int u; float f; } v; v.u = u << 16;
    return v.f;
}
// add two bf16 pairs (packed in uint), result packed bf16 pair
__device__ __forceinline__ unsigned int bfadd2(unsigned int a, unsigned int b) {
    float lo = bf2f(a & 0xffffu) + bf2f(b & 0xffffu);
    float hi = bf2f(a >> 16) + bf2f(b >> 16);
    return (unsigned int)f2bf(lo) | ((unsigned int)f2bf(hi) << 16);
}

// ---------------------------------------------------------------------------
// hb[t] = bf16(elu(x @ W + b)); x:[n,64], W:[64,128]
__global__ __launch_bounds__(128) void k_input_linear(
    const float* __restrict__ x, const float* __restrict__ W,
    const float* __restrict__ b, unsigned short* __restrict__ hb, int n)
{
    __shared__ float Ws[64 * H];
    __shared__ float xs[16 * 64];
    __shared__ unsigned short os[16 * H];
    const int j = threadIdx.x;
    for (int i = j; i < 64 * H; i += 128) Ws[i] = W[i];
    const float bj = b[j];

    for (int r0 = blockIdx.x * 16; r0 < n; r0 += gridDim.x * 16) {
        const int nrows = min(16, n - r0);
        __syncthreads();
        for (int i = j; i < nrows * 64; i += 128) xs[i] = x[(size_t)r0 * 64 + i];
        __syncthreads();
        for (int i = 0; i < nrows; ++i) {
            float acc = bj;
#pragma unroll
            for (int k = 0; k < 64; k += 4) {
                float4 xv = *(const float4*)&xs[i * 64 + k];
                acc += xv.x * Ws[(k + 0) * H + j] + xv.y * Ws[(k + 1) * H + j]
                     + xv.z * Ws[(k + 2) * H + j] + xv.w * Ws[(k + 3) * H + j];
            }
            os[i * H + j] = f2bf(eluf(acc));
        }
        __syncthreads();
        uint2* d = (uint2*)&hb[(size_t)r0 * H];
        const uint2* s2 = (const uint2*)os;
        for (int i = j; i < nrows * 32; i += 128) d[i] = s2[i];
    }
}

// --------------------------- CSR build -------------------------------------
__global__ __launch_bounds__(256) void k_hist(
    const int* __restrict__ dst, int* __restrict__ deg, int E)
{
    for (int e = blockIdx.x * 256 + threadIdx.x; e < E; e += gridDim.x * 256)
        atomicAdd(&deg[dst[e]], 1);
}

__global__ __launch_bounds__(256) void k_scan_partial(
    const int* __restrict__ deg, int* __restrict__ bsum, int n)
{
    __shared__ int s[256];
    const int tid = threadIdx.x;
    const int idx = blockIdx.x * 256 + tid;
    s[tid] = idx < n ? deg[idx] : 0;
    __syncthreads();
    for (int off = 128; off > 0; off >>= 1) {
        if (tid < off) s[tid] += s[tid + off];
        __syncthreads();
    }
    if (tid == 0) bsum[blockIdx.x] = s[0];
}

// block-parallel exclusive scan of block sums (nb <= 512), writes ptr[n]=total
__global__ __launch_bounds__(512) void k_scan_mid(
    int* bsum, int nb, int* ptr, int n)
{
    __shared__ int s[512];
    const int tid = threadIdx.x;
    const int v = tid < nb ? bsum[tid] : 0;
    s[tid] = v;
    __syncthreads();
    for (int off = 1; off < 512; off <<= 1) {
        int t = (tid >= off) ? s[tid - off] : 0;
        __syncthreads();
        s[tid] += t;
        __syncthreads();
    }
    if (tid < nb) bsum[tid] = s[tid] - v;   // exclusive
    if (tid == nb - 1) ptr[n] = s[tid];     // total
}

__global__ __launch_bounds__(256) void k_scan_final(
    const int* __restrict__ deg, const int* __restrict__ bsum,
    int* __restrict__ ptr, int* __restrict__ cursor, int n)
{
    __shared__ int s[256];
    const int tid = threadIdx.x;
    const int idx = blockIdx.x * 256 + tid;
    const int v = idx < n ? deg[idx] : 0;
    s[tid] = v;
    __syncthreads();
    for (int off = 1; off < 256; off <<= 1) {
        int t = (tid >= off) ? s[tid - off] : 0;
        __syncthreads();
        s[tid] += t;
        __syncthreads();
    }
    if (idx < n) {
        int excl = s[tid] - v + bsum[blockIdx.x];
        ptr[idx] = excl;
        cursor[idx] = excl;
    }
}

// scatter edges into dst-grouped order; ea packed to bf16x3 in 8 bytes
__global__ __launch_bounds__(256) void k_scatter(
    const int* __restrict__ src, const int* __restrict__ dst,
    const float* __restrict__ ea, int* __restrict__ cursor,
    int* __restrict__ csr_src, uint2* __restrict__ csr_ea, int E)
{
    for (int e = blockIdx.x * 256 + threadIdx.x; e < E; e += gridDim.x * 256) {
        const int d = dst[e];
        const int pos = atomicAdd(&cursor[d], 1);
        csr_src[pos] = src[e];
        uint2 p;
        p.x = (unsigned int)f2bf(ea[(size_t)3 * e + 0])
            | ((unsigned int)f2bf(ea[(size_t)3 * e + 1]) << 16);
        p.y = (unsigned int)f2bf(ea[(size_t)3 * e + 2]);
        csr_ea[pos] = p;
    }
}

// ---------------------------------------------------------------------------
// Weight prep: W1,W2 [21][128k][128c] f32 -> wp [21][2][128c][128k] bf16
__global__ __launch_bounds__(256) void k_wprep(
    const float* __restrict__ W1, const float* __restrict__ W2,
    unsigned short* __restrict__ wp, int total)
{
    for (int i = blockIdx.x * 256 + threadIdx.x; i < total; i += gridDim.x * 256) {
        int lr = i >> 14, rem = i & 16383;
        int c = rem >> 7, k = rem & 127;
        wp[(size_t)(lr * 2 + 0) * 16384 + rem] = f2bf(W1[(size_t)lr * 16384 + k * H + c]);
        wp[(size_t)(lr * 2 + 1) * 16384 + rem] = f2bf(W2[(size_t)lr * 16384 + k * H + c]);
    }
}

// ---------------------------------------------------------------------------
// Gather aggregation: agg[d] = bf16( sum_e relu(hb[src] + ea@eW + eb) ).
// 1 node per 64-lane group (lane = 2 cols), 4 nodes per 256-thr block.
__global__ __launch_bounds__(256) void k_agg(
    const int* __restrict__ ptr, const int* __restrict__ csr_src,
    const uint2* __restrict__ csr_ea, const float* __restrict__ eW,
    const float* __restrict__ eb, const unsigned short* __restrict__ hb,
    unsigned short* __restrict__ agg, int nd)
{
    const int lane = threadIdx.x & 63;
    const int t2 = lane << 1;
    const int which = threadIdx.x >> 6;
    const float w00 = eW[t2],         w01 = eW[t2 + 1];
    const float w10 = eW[H + t2],     w11 = eW[H + t2 + 1];
    const float w20 = eW[2 * H + t2], w21 = eW[2 * H + t2 + 1];
    const float b0 = eb[t2], b1v = eb[t2 + 1];
    for (int d = blockIdx.x * 4 + which; d < nd; d += gridDim.x * 4) {
        const int p0 = ptr[d], p1 = ptr[d + 1];
        float acc0 = 0.f, acc1 = 0.f;
        for (int i = p0; i < p1; ++i) {
            const int s = csr_src[i];
            const uint2 ep = csr_ea[i];
            const float a0 = bf2f(ep.x & 0xffffu);
            const float a1 = bf2f(ep.x >> 16);
            const float a2 = bf2f(ep.y & 0xffffu);
            const unsigned int hv = ((const unsigned int*)&hb[(size_t)s * H])[lane];
            acc0 += fmaxf(bf2f(hv & 0xffffu) + a0 * w00 + a1 * w10 + a2 * w20 + b0, 0.f);
            acc1 += fmaxf(bf2f(hv >> 16)     + a0 * w01 + a1 * w11 + a2 * w21 + b1v, 0.f);
        }
        ((unsigned int*)agg)[d * 64 + lane] =
            (unsigned int)f2bf(acc0) | ((unsigned int)f2bf(acc1) << 16);
    }
}

// ---------------------------------------------------------------------------
// Fused multi-relation MFMA MLP for one dst type (h in bf16):
//   hnew = elu( sum_rel (relu((hb+agg_rel)@W1*bn+..)@W2 + b2) + hb )
// fin=0: write bf16 hb (coalesced via LDS). fin=1: write f32 to fout (scattered).
template<int NREL>
__global__ __launch_bounds__(512, 4) void k_mlp_fused(
    const unsigned short* __restrict__ hb, unsigned short* __restrict__ hbw,
    float* __restrict__ fout,
    const unsigned short* __restrict__ wprep,
    const float* __restrict__ b1g, const float* __restrict__ g1g,
    const float* __restrict__ be1g, const float* __restrict__ b2g,
    const unsigned short* __restrict__ aggA,
    const unsigned short* __restrict__ aggB,
    const unsigned short* __restrict__ aggC,
    int lrA, int lrB, int lrC, int n, int fin)
{
    __shared__ unsigned short zt[128 * H];   // 32 KB, XOR-swizzled staging
    __shared__ unsigned short a1t[128 * H];  // 32 KB

    const unsigned short* aggp[3] = {aggA, aggB, aggC};
    const int lrv[3] = {lrA, lrB, lrC};

    const int tid = threadIdx.x;
    const int lane = tid & 63;
    const int wave = tid >> 6;
    const int wr = wave >> 2;      // 0..1
    const int wc = wave & 3;       // 0..3
    const int l15 = lane & 15;
    const int lq  = lane >> 4;
    const int c0 = wc * 32 + l15;

    const int r0 = blockIdx.x * 128;
    const int rows = min(128, n - r0);

    const float bn_inv = 0.99999500003749977f;
    float b1c[NREL][2], sc[NREL][2], bec[NREL][2], b2sum[2] = {0.f, 0.f};
#pragma unroll
    for (int rl = 0; rl < NREL; ++rl)
#pragma unroll
        for (int nf = 0; nf < 2; ++nf) {
            const int c = lrv[rl] * H + c0 + nf * 16;
            b1c[rl][nf] = b1g[c]; sc[rl][nf] = g1g[c] * bn_inv;
            bec[rl][nf] = be1g[c]; b2sum[nf] += b2g[c];
        }

    const f32x4 Z4 = {0.f, 0.f, 0.f, 0.f};
    f32x4 acc2[4][2];
#pragma unroll
    for (int rb = 0; rb < 4; ++rb)
#pragma unroll
        for (int nf = 0; nf < 2; ++nf) acc2[rb][nf] = Z4;

#pragma unroll
    for (int rl = 0; rl < NREL; ++rl) {
        // weight fragments (global bf16 -> regs)
        const unsigned short* wp = wprep + (size_t)lrv[rl] * 32768;
        short8 w1f[2][4], w2f[2][4];
#pragma unroll
        for (int nf = 0; nf < 2; ++nf) {
            const int c = c0 + nf * 16;
#pragma unroll
            for (int kc = 0; kc < 4; ++kc) {
                w1f[nf][kc] = *(const short8*)&wp[c * H + kc * 32 + (lq << 3)];
                w2f[nf][kc] = *(const short8*)&wp[16384 + c * H + kc * 32 + (lq << 3)];
            }
        }
        // stage z = hb + agg (bf16, swizzled); uint4 = 8 bf16 per thread-iter
        const unsigned short* ag = aggp[rl];
        if (rows == 128) {
            uint4 hv[4], av[4];
#pragma unroll
            for (int it = 0; it < 4; ++it) {
                const int idx = tid + it * 512;
                const int row = idx >> 4, cg = (idx & 15) << 3;
                hv[it] = *(const uint4*)&hb[(size_t)(r0 + row) * H + cg];
                av[it] = *(const uint4*)&ag[(size_t)(r0 + row) * H + cg];
            }
#pragma unroll
            for (int it = 0; it < 4; ++it) {
                const int idx = tid + it * 512;
                const int row = idx >> 4, cg = (idx & 15) << 3;
                uint4 p;
                p.x = bfadd2(hv[it].x, av[it].x);
                p.y = bfadd2(hv[it].y, av[it].y);
                p.z = bfadd2(hv[it].z, av[it].z);
                p.w = bfadd2(hv[it].w, av[it].w);
                *(uint4*)&zt[row * H + (cg ^ ((row & 7) << 3))] = p;
            }
        } else {
            for (int idx = tid; idx < rows * 16; idx += 512) {
                const int row = idx >> 4, cg = (idx & 15) << 3;
                uint4 hv = *(const uint4*)&hb[(size_t)(r0 + row) * H + cg];
                uint4 av = *(const uint4*)&ag[(size_t)(r0 + row) * H + cg];
                uint4 p;
                p.x = bfadd2(hv.x, av.x);
                p.y = bfadd2(hv.y, av.y);
                p.z = bfadd2(hv.z, av.z);
                p.w = bfadd2(hv.w, av.w);
                *(uint4*)&zt[row * H + (cg ^ ((row & 7) << 3))] = p;
            }
        }
        __syncthreads();  // A: zt ready

        // GEMM1: zt @ W1
        f32x4 acc1[4][2];
#pragma unroll
        for (int rb = 0; rb < 4; ++rb)
#pragma unroll
            for (int nf = 0; nf < 2; ++nf) acc1[rb][nf] = Z4;
#pragma unroll
        for (int kc = 0; kc < 4; ++kc) {
            const int kb = kc * 32 + (lq << 3);
            short8 af[4];
#pragma unroll
            for (int rb = 0; rb < 4; ++rb) {
                const int row = wr * 64 + rb * 16 + l15;
                af[rb] = *(const short8*)&zt[row * H + (kb ^ ((row & 7) << 3))];
            }
#pragma unroll
            for (int rb = 0; rb < 4; ++rb)
#pragma unroll
                for (int nf = 0; nf < 2; ++nf)
                    acc1[rb][nf] = __builtin_amdgcn_mfma_f32_16x16x32_bf16(
                        af[rb], w1f[nf][kc], acc1[rb][nf], 0, 0, 0);
        }
        // epilogue1: BN+ReLU -> a1t
#pragma unroll
        for (int rb = 0; rb < 4; ++rb)
#pragma unroll
            for (int nf = 0; nf < 2; ++nf) {
                const int col = c0 + nf * 16;
#pragma unroll
                for (int rg = 0; rg < 4; ++rg) {
                    const int row = wr * 64 + rb * 16 + (lq << 2) + rg;
                    float v = fmaxf((acc1[rb][nf][rg] + b1c[rl][nf]) * sc[rl][nf]
                                    + bec[rl][nf], 0.f);
                    a1t[row * H + (col ^ ((row & 7) << 3))] = f2bf(v);
                }
            }
        __syncthreads();  // B: a1t ready

        // GEMM2: a1t @ W2, C chained in acc2
#pragma unroll
        for (int kc = 0; kc < 4; ++kc) {
            const int kb = kc * 32 + (lq << 3);
            short8 af[4];
#pragma unroll
            for (int rb = 0; rb < 4; ++rb) {
                const int row = wr * 64 + rb * 16 + l15;
                af[rb] = *(const short8*)&a1t[row * H + (kb ^ ((row & 7) << 3))];
            }
#pragma unroll
            for (int rb = 0; rb < 4; ++rb)
#pragma unroll
                for (int nf = 0; nf < 2; ++nf)
                    acc2[rb][nf] = __builtin_amdgcn_mfma_f32_16x16x32_bf16(
                        af[rb], w2f[nf][kc], acc2[rb][nf], 0, 0, 0);
        }
    }

    // ---- final epilogue: hnew = elu(acc2 + sum(b2) + hb) ----
    if (fin) {
#pragma unroll
        for (int rb = 0; rb < 4; ++rb)
#pragma unroll
            for (int nf = 0; nf < 2; ++nf) {
                const int col = c0 + nf * 16;
#pragma unroll
                for (int rg = 0; rg < 4; ++rg) {
                    const int row = wr * 64 + rb * 16 + (lq << 2) + rg;
                    if (row < rows) {
                        const size_t o = (size_t)(r0 + row) * H + col;
                        fout[o] = eluf(acc2[rb][nf][rg] + b2sum[nf]
                                       + bf2f((unsigned int)hb[o]));
                    }
                }
            }
    } else {
#pragma unroll
        for (int rb = 0; rb < 4; ++rb)
#pragma unroll
            for (int nf = 0; nf < 2; ++nf) {
                const int col = c0 + nf * 16;
#pragma unroll
                for (int rg = 0; rg < 4; ++rg) {
                    const int row = wr * 64 + rb * 16 + (lq << 2) + rg;
                    if (row < rows) {
                        const size_t o = (size_t)(r0 + row) * H + col;
                        zt[row * H + col] = f2bf(eluf(acc2[rb][nf][rg] + b2sum[nf]
                                                      + bf2f((unsigned int)hb[o])));
                    }
                }
            }
        __syncthreads();
        uint2* d = (uint2*)&hbw[(size_t)r0 * H];
        const uint2* s2 = (const uint2*)zt;
        for (int idx = tid; idx < rows * 32; idx += 512) d[idx] = s2[idx];
    }
}

static inline int imin(int a, int b) { return a < b ? a : b; }
static inline size_t alignup(size_t x) { return (x + 255) & ~(size_t)255; }

extern "C" void kernel_launch(void* const* d_in, const int* in_sizes, int n_in,
                              void* d_out, int out_size, void* d_ws, size_t ws_size,
                              hipStream_t stream) {
    const float* xin[3] = {(const float*)d_in[0], (const float*)d_in[1], (const float*)d_in[2]};
    const int* src[7]; const int* dst[7]; const float* ea[7]; int E[7];
    for (int r = 0; r < 7; ++r) {
        src[r] = (const int*)d_in[3 + 3 * r];
        dst[r] = (const int*)d_in[4 + 3 * r];
        ea[r]  = (const float*)d_in[5 + 3 * r];
        E[r]   = in_sizes[3 + 3 * r];
    }
    const float* linW[3] = {(const float*)d_in[24], (const float*)d_in[26], (const float*)d_in[28]};
    const float* linb[3] = {(const float*)d_in[25], (const float*)d_in[27], (const float*)d_in[29]};
    const float* eW  = (const float*)d_in[30];
    const float* ebp = (const float*)d_in[31];
    const float* W1  = (const float*)d_in[32];
    const float* b1  = (const float*)d_in[33];
    const float* g1  = (const float*)d_in[34];
    const float* be1 = (const float*)d_in[35];
    const float* W2  = (const float*)d_in[36];
    const float* b2  = (const float*)d_in[37];

    const int NSn[3]  = {in_sizes[0] / 64, in_sizes[1] / 64, in_sizes[2] / 64};
    const int NTOT = NSn[0] + NSn[1] + NSn[2];
    const int noff[3] = {0, NSn[0], NSn[0] + NSn[1]};
    int maxn = NSn[0]; if (NSn[1] > maxn) maxn = NSn[1]; if (NSn[2] > maxn) maxn = NSn[2];

    float* fout = (float*)d_out;

    // workspace carve-up (~142 MB)
    char* wsb = (char*)d_ws;
    size_t off = 0;
    unsigned short* hb = (unsigned short*)(wsb + off); off = alignup(off + (size_t)NTOT * H * 2);
    unsigned short* aggb[7];
    for (int r = 0; r < 7; ++r) {
        int nd = NSn[DST_T_[r]];
        aggb[r] = (unsigned short*)(wsb + off); off = alignup(off + (size_t)nd * H * 2);
    }
    unsigned short* wprep = (unsigned short*)(wsb + off); off = alignup(off + (size_t)21 * 32768 * 2);
    int* deg    = (int*)(wsb + off); off = alignup(off + (size_t)maxn * 4);
    int* cursor = (int*)(wsb + off); off = alignup(off + (size_t)maxn * 4);
    int* bsum   = (int*)(wsb + off); off = alignup(off + 4096);
    int* ptrs[7]; int* csrs[7]; uint2* ceas[7];
    for (int r = 0; r < 7; ++r) {
        int nd = NSn[DST_T_[r]];
        ptrs[r] = (int*)(wsb + off); off = alignup(off + (size_t)(nd + 1) * 4);
    }
    for (int r = 0; r < 7; ++r) {
        csrs[r] = (int*)(wsb + off); off = alignup(off + (size_t)E[r] * 4);
    }
    for (int r = 0; r < 7; ++r) {
        ceas[r] = (uint2*)(wsb + off); off = alignup(off + (size_t)E[r] * 8);
    }

    // ---- CSR build + weight prep ----
    for (int r = 0; r < 7; ++r) {
        const int nd = NSn[DST_T_[r]];
        const int nb = (nd + 255) / 256;
        hipMemsetAsync(deg, 0, (size_t)nd * 4, stream);
        k_hist<<<imin((E[r] + 255) / 256, 2048), 256, 0, stream>>>(dst[r], deg, E[r]);
        k_scan_partial<<<nb, 256, 0, stream>>>(deg, bsum, nd);
        k_scan_mid<<<1, 512, 0, stream>>>(bsum, nb, ptrs[r], nd);
        k_scan_final<<<nb, 256, 0, stream>>>(deg, bsum, ptrs[r], cursor, nd);
        k_scatter<<<imin((E[r] + 255) / 256, 2048), 256, 0, stream>>>(
            src[r], dst[r], ea[r], cursor, csrs[r], ceas[r], E[r]);
    }
    k_wprep<<<1344, 256, 0, stream>>>(W1, W2, wprep, 21 * 16384);

    // ---- input embeddings (bf16 h) ----
    for (int t = 0; t < 3; ++t) {
        int n = NSn[t];
        k_input_linear<<<imin((n + 15) / 16, 2048), 128, 0, stream>>>(
            xin[t], linW[t], linb[t], hb + (size_t)noff[t] * H, n);
    }

    // ---- layers ----
    for (int l = 0; l < 3; ++l) {
        const int fin = (l == 2) ? 1 : 0;
        for (int r = 0; r < 7; ++r) {
            const int s = SRC_T_[r];
            const int nd = NSn[DST_T_[r]];
            const int lr = l * 7 + r;
            k_agg<<<(nd + 3) / 4, 256, 0, stream>>>(
                ptrs[r], csrs[r], ceas[r],
                eW + (size_t)lr * 3 * H, ebp + (size_t)lr * H,
                hb + (size_t)noff[s] * H, aggb[r], nd);
        }
        // dst type 0: relations {0,2}
        k_mlp_fused<2><<<(NSn[0] + 127) / 128, 512, 0, stream>>>(
            hb + (size_t)noff[0] * H, hb + (size_t)noff[0] * H,
            fout + (size_t)noff[0] * H, wprep,
            b1, g1, be1, b2, aggb[0], aggb[2], aggb[0],
            l * 7 + 0, l * 7 + 2, 0, NSn[0], fin);
        // dst type 1: relations {1,3,5}
        k_mlp_fused<3><<<(NSn[1] + 127) / 128, 512, 0, stream>>>(
            hb + (size_t)noff[1] * H, hb + (size_t)noff[1] * H,
            fout + (size_t)noff[1] * H, wprep,
            b1, g1, be1, b2, aggb[1], aggb[3], aggb[5],
            l * 7 + 1, l * 7 + 3, l * 7 + 5, NSn[1], fin);
        // dst type 2: relations {4,6}
        k_mlp_fused<2><<<(NSn[2] + 127) / 128, 512, 0, stream>>>(
            hb + (size_t)noff[2] * H, hb + (size_t)noff[2] * H,
            fout + (size_t)noff[2] * H, wprep,
            b1, g1, be1, b2, aggb[4], aggb[6], aggb[4],
            l * 7 + 4, l * 7 + 6, 0, NSn[2], fin);
    }
}